// Round 4
// baseline (117.207 us; speedup 1.0000x reference)
//
#include <hip/hip_runtime.h>
#include <hip/hip_bf16.h>

// ChebyKANLinear: y[b,j] = sum_i sum_k T_k(tanh(x[b,i])) * C[i,j,k]
//   x: (16384, 512) f32; C: (512, 512, 9) f32; y: (16384, 512) f32
// GEMM: M=16384, N=512, K=4608 (kflat = k*512 + i).
// v4: wave tile 32x64 (m'=2 -> B-frag reused 2x, halves LDS reads) +
//     conflict-free slot-major B LDS layout [s][j][8] with matching W2 global
//     layout so global_load_lds stays linear AND coalesced.
// 8 waves = 4(m) x 2(n); BM=128, BN=128, step = 32 kflat; double-buffered.

typedef __bf16 bf16x8 __attribute__((ext_vector_type(8)));
typedef float  f32x4  __attribute__((ext_vector_type(4)));

#define DIM  512
#define KDEG 9
#define BM   128
#define BN   128
#define NIC  16                  // 512 / 32 i-chunks
#define STEP_ELEMS (4 * DIM * 8) // 16384 bf16 per kstep slab of W2

// ---- pack kernel: C[i][j][k] -> W2[(k*16+ic)][s][j][e]  (i = ic*32+s*8+e) ----
// thread t: j = t&511, s = (t>>9)&3, ic = t>>11;  32768 threads.
__global__ void pack_w_kernel(const float* __restrict__ coeffs,
                              __bf16* __restrict__ W2) {
    int t  = blockIdx.x * blockDim.x + threadIdx.x;
    int j  = t & (DIM - 1);
    int s  = (t >> 9) & 3;
    int ic = t >> 11;

    bf16x8 v[KDEG];
#pragma unroll
    for (int e = 0; e < 8; ++e) {
        int i = ic * 32 + s * 8 + e;
        const float* src = coeffs + ((size_t)i * DIM + j) * KDEG;
#pragma unroll
        for (int k = 0; k < KDEG; ++k)
            v[k][e] = (__bf16)src[k];
    }
#pragma unroll
    for (int k = 0; k < KDEG; ++k) {
        size_t off = (size_t)(k * 16 + ic) * STEP_ELEMS + ((size_t)s * DIM + j) * 8;
        *reinterpret_cast<bf16x8*>(W2 + off) = v[k];
    }
}

// ---------------- fused Chebyshev-basis + MFMA GEMM -----------------------------
__global__ __launch_bounds__(512, 4) void cheby_gemm_kernel(
    const float* __restrict__ x,
    const __bf16* __restrict__ W2,
    float* __restrict__ out)
{
    // B tile double buffer, slot-major: elem (s*BN + j)*8 + e ; 8KB per buffer
    __shared__ __bf16 Bl[2][4 * BN * 8];

    const int tid  = threadIdx.x;
    const int lane = tid & 63;
    const int wid  = tid >> 6;     // 0..7
    const int wr   = wid & 3;      // 0..3  m-group (32 rows each)
    const int wc   = wid >> 2;     // 0..1  n-group (64 cols each)
    const int l15  = lane & 15;
    const int l4   = lane >> 4;    // 0..3
    const int bm   = blockIdx.y * BM;
    const int bn   = blockIdx.x * BN;

    // staging: thread t loads 16B chunk (s = t>>7, j_local = t&127)
    const __bf16* wbase = W2 + ((size_t)(tid >> 7) * DIM + bn + (tid & 127)) * 8;
    __bf16* ldst0 = &Bl[0][0] + tid * 8;
    __bf16* ldst1 = &Bl[1][0] + tid * 8;

    // A: two row-frags per wave; lane holds 8 i's at slot l4
    const float* xrow0 = x + (size_t)(bm + wr * 32 + l15) * DIM + l4 * 8;
    const float* xrow1 = xrow0 + 16 * DIM;

    // B frag read base: elem (l4*128 + wc*64 + nf*16 + l15)*8
    const __bf16* bbase0 = &Bl[0][0] + (l4 * BN + wc * 64 + l15) * 8;
    const __bf16* bbase1 = &Bl[1][0] + (l4 * BN + wc * 64 + l15) * 8;

    f32x4 acc[2][4] = {};

    bf16x8 aone;
#pragma unroll
    for (int e = 0; e < 8; ++e) aone[e] = (__bf16)1.0f;

    // prologue: stage kstep 0 (k=0, ic=0) into buf 0
    __builtin_amdgcn_global_load_lds(wbase, ldst0, 16, 0, 0);

    int cur = 0;
    for (int ic = 0; ic < NIC; ++ic) {
        // load x fragments for this ic, compute t = tanh(x)
        f32x4 x0a = *reinterpret_cast<const f32x4*>(xrow0 + ic * 32);
        f32x4 x0b = *reinterpret_cast<const f32x4*>(xrow0 + ic * 32 + 4);
        f32x4 x1a = *reinterpret_cast<const f32x4*>(xrow1 + ic * 32);
        f32x4 x1b = *reinterpret_cast<const f32x4*>(xrow1 + ic * 32 + 4);

        float th2[2][8], Tk[2][8], Tm[2][8];
#pragma unroll
        for (int e = 0; e < 8; ++e) {
            float xv0 = (e < 4) ? x0a[e] : x0b[e - 4];
            float xv1 = (e < 4) ? x1a[e] : x1b[e - 4];
            float p0 = __builtin_amdgcn_exp2f(xv0 * 2.8853900817779268f);
            float p1 = __builtin_amdgcn_exp2f(xv1 * 2.8853900817779268f);
            float t0 = 1.0f - 2.0f * __builtin_amdgcn_rcpf(p0 + 1.0f);
            float t1 = 1.0f - 2.0f * __builtin_amdgcn_rcpf(p1 + 1.0f);
            Tk[0][e] = t0;  th2[0][e] = t0 + t0;  Tm[0][e] = 1.0f;
            Tk[1][e] = t1;  th2[1][e] = t1 + t1;  Tm[1][e] = 1.0f;
        }

#pragma unroll
        for (int k = 0; k < KDEG; ++k) {
            __syncthreads();   // staging into cur complete; prev reads of cur^1 done

            // stage next kstep into other buffer
            if ((k < KDEG - 1) || (ic + 1 < NIC)) {
                const int nk  = (k < KDEG - 1) ? k + 1 : 0;
                const int nic = (k < KDEG - 1) ? ic : ic + 1;
                __builtin_amdgcn_global_load_lds(
                    wbase + (size_t)(nk * 16 + nic) * STEP_ELEMS,
                    cur ? ldst0 : ldst1, 16, 0, 0);
            }

            // A fragments for this k
            bf16x8 af0, af1;
            if (k == 0) {
                af0 = aone; af1 = aone;
            } else {
#pragma unroll
                for (int e = 0; e < 8; ++e) {
                    af0[e] = (__bf16)Tk[0][e];
                    af1[e] = (__bf16)Tk[1][e];
                }
                if (k < KDEG - 1) {
#pragma unroll
                    for (int e = 0; e < 8; ++e) {
                        float Tn0 = __builtin_fmaf(th2[0][e], Tk[0][e], -Tm[0][e]);
                        float Tn1 = __builtin_fmaf(th2[1][e], Tk[1][e], -Tm[1][e]);
                        Tm[0][e] = Tk[0][e];  Tk[0][e] = Tn0;
                        Tm[1][e] = Tk[1][e];  Tk[1][e] = Tn1;
                    }
                }
            }

            // B frags (conflict-free: consecutive lanes -> consecutive 16B) + MFMA
            const __bf16* bb = cur ? bbase1 : bbase0;
#pragma unroll
            for (int nf = 0; nf < 4; ++nf) {
                bf16x8 b = *reinterpret_cast<const bf16x8*>(bb + nf * 16 * 8);
                acc[0][nf] = __builtin_amdgcn_mfma_f32_16x16x32_bf16(af0, b, acc[0][nf], 0, 0, 0);
                acc[1][nf] = __builtin_amdgcn_mfma_f32_16x16x32_bf16(af1, b, acc[1][nf], 0, 0, 0);
            }
            cur ^= 1;
        }
    }

    // epilogue: C/D layout col=lane&15, row=(lane>>4)*4+r
#pragma unroll
    for (int mf = 0; mf < 2; ++mf)
#pragma unroll
        for (int r = 0; r < 4; ++r) {
            const int row = bm + wr * 32 + mf * 16 + l4 * 4 + r;
            float* orow = out + (size_t)row * DIM + bn + wc * 64 + l15;
#pragma unroll
            for (int nf = 0; nf < 4; ++nf)
                orow[nf * 16] = acc[mf][nf][r];
        }
}

extern "C" void kernel_launch(void* const* d_in, const int* in_sizes, int n_in,
                              void* d_out, int out_size, void* d_ws, size_t ws_size,
                              hipStream_t stream) {
    const float* x      = (const float*)d_in[0];   // (16384, 512)
    const float* coeffs = (const float*)d_in[1];   // (512, 512, 9)
    float* out          = (float*)d_out;           // (16384, 512)
    __bf16* W2          = (__bf16*)d_ws;           // 144*16384 bf16 = 4.7MB

    pack_w_kernel<<<(DIM * 64) / 256, 256, 0, stream>>>(coeffs, W2);

    // grid = (N/BN, M/BM) = (4, 128) = 512 blocks = 2 per CU
    cheby_gemm_kernel<<<dim3(DIM / BN, 16384 / BM), 512, 0, stream>>>(x, W2, out);
}